// Round 21
// baseline (121.720 us; speedup 1.0000x reference)
//
#include <hip/hip_runtime.h>
#include <hip/hip_fp16.h>
#include <math.h>

#define NN 50000
#define NE 800000
#define ETOT (NE + NN)
#define INC 128
#define F1 64
#define NH 8
#define OC 16
#define NEG 0.2f
#define BSH 7         // 128 dsts per bucket
#define NBUK 391      // ceil(NN/128)
#define CHUNK_A 4096
#define NBLK_A ((ETOT + CHUNK_A - 1) / CHUNK_A)   // 208
#define G1TILE 64
#define NBLK_G1 ((NN + G1TILE - 1) / G1TILE)      // 782
#define XR 136        // LDS row stride in halves (+8 pad: bank-spread)

typedef _Float16 half8 __attribute__((ext_vector_type(8)));
typedef float f32x4 __attribute__((ext_vector_type(4)));

__device__ __forceinline__ float leaky(float x){ return x > 0.f ? x : NEG * x; }

__device__ __forceinline__ void getsd(const int* __restrict__ ei, int e, int& s, int& d){
    if (e < NE){ s = ei[e]; d = ei[NE + e]; }
    else { s = e - NE; d = s; }   // self-loops appended
}

// ---------------- CSR build: two-level binning (R13-proven) ----------------

__global__ __launch_bounds__(256) void zero_gbcnt(int* __restrict__ gbcnt){
    int i = blockIdx.x*256 + threadIdx.x;
    if (i < NBUK) gbcnt[i] = 0;
}

__global__ __launch_bounds__(256) void bucket_hist(const int* __restrict__ ei, int* __restrict__ gbcnt){
    __shared__ int bcnt[NBUK];
    int tid = threadIdx.x;
    for (int j = tid; j < NBUK; j += 256) bcnt[j] = 0;
    __syncthreads();
    int e0 = blockIdx.x * CHUNK_A;
    int e1 = e0 + CHUNK_A; if (e1 > ETOT) e1 = ETOT;
    for (int e = e0 + tid; e < e1; e += 256){
        int d = (e < NE) ? ei[NE + e] : e - NE;
        atomicAdd(&bcnt[d >> BSH], 1);
    }
    __syncthreads();
    for (int j = tid; j < NBUK; j += 256)
        if (bcnt[j]) atomicAdd(&gbcnt[j], bcnt[j]);
}

__global__ __launch_bounds__(512) void bucket_scan(const int* __restrict__ gbcnt,
        int* __restrict__ gboff, int* __restrict__ gbcur){
    __shared__ int s[512];
    int t = threadIdx.x;
    int v = (t < NBUK) ? gbcnt[t] : 0;
    s[t] = v; __syncthreads();
    for (int off = 1; off < 512; off <<= 1){
        int u = (t >= off) ? s[t - off] : 0;
        __syncthreads();
        s[t] += u;
        __syncthreads();
    }
    if (t < NBUK){ int ex = s[t] - v; gboff[t] = ex; gbcur[t] = ex; }
    if (t == 0) gboff[NBUK] = ETOT;
}

// fused: blocks [0, NBLK_A) = bucket_scatter; blocks [NBLK_A, NBLK_A+NBLK_G1) = MFMA gemm1 (+att1)
__global__ __launch_bounds__(256) void scatter_gemm1(const int* __restrict__ ei,
        int* __restrict__ gbcur, unsigned* __restrict__ packed,
        const float* __restrict__ x, const float* __restrict__ W1,
        const float* __restrict__ att_s, const float* __restrict__ att_d,
        __half* __restrict__ h1h, float* __restrict__ a_src, float* __restrict__ a_dst){
    __shared__ _Float16 xs[64*XR];   // 17.4 KB (scatter branch aliases as bcnt)
    __shared__ _Float16 wsl[64*XR];  // 17.4 KB
    int tid = threadIdx.x;
    if (blockIdx.x < NBLK_A){
        // ---- bucket_scatter (R13-proven; bcnt aliases xs) ----
        int* bcnt = (int*)xs;
        for (int j = tid; j < NBUK; j += 256) bcnt[j] = 0;
        __syncthreads();
        int e0 = blockIdx.x * CHUNK_A;
        int e1 = e0 + CHUNK_A; if (e1 > ETOT) e1 = ETOT;
        for (int e = e0 + tid; e < e1; e += 256){
            int d = (e < NE) ? ei[NE + e] : e - NE;
            atomicAdd(&bcnt[d >> BSH], 1);
        }
        __syncthreads();
        for (int j = tid; j < NBUK; j += 256){
            int c = bcnt[j];
            bcnt[j] = c ? atomicAdd(&gbcur[j], c) : 0;
        }
        __syncthreads();
        for (int e = e0 + tid; e < e1; e += 256){
            int s, d; getsd(ei, e, s, d);
            int pos = atomicAdd(&bcnt[d >> BSH], 1);
            packed[pos] = ((unsigned)s << 16) | (unsigned)d;
        }
        return;
    }
    // ---- MFMA gemm1 + fused att1 (R18-proven) ----
    int base = (blockIdx.x - NBLK_A) * G1TILE;
    for (int i = tid; i < F1*INC; i += 256){
        int o = i >> 7, k = i & 127;
        wsl[o*XR + k] = (_Float16)W1[i];
    }
    for (int f = tid; f < 64*32; f += 256){
        int row = f >> 5, c4 = f & 31;
        int n = base + row;
        float4 v = (n < NN) ? reinterpret_cast<const float4*>(x)[n*32 + c4]
                            : make_float4(0.f,0.f,0.f,0.f);
        _Float16* p = &xs[row*XR + c4*4];
        p[0] = (_Float16)v.x; p[1] = (_Float16)v.y;
        p[2] = (_Float16)v.z; p[3] = (_Float16)v.w;
    }
    __syncthreads();
    int w = tid >> 6, lane = tid & 63;
    int mrow = lane & 15, kg = lane >> 4;
    int nodeb = w*16;
    half8 afrag[4];
    #pragma unroll
    for (int kk = 0; kk < 4; ++kk){
        const _Float16* pa = &xs[(nodeb + mrow)*XR + kk*32 + kg*4];
        *(unsigned long long*)&afrag[kk]       = *(const unsigned long long*)pa;
        *((unsigned long long*)&afrag[kk] + 1) = *(const unsigned long long*)(pa + 16);
    }
    f32x4 acc[4];
    #pragma unroll
    for (int ot = 0; ot < 4; ++ot) acc[ot] = (f32x4){0.f,0.f,0.f,0.f};
    #pragma unroll
    for (int ot = 0; ot < 4; ++ot){
        #pragma unroll
        for (int kk = 0; kk < 4; ++kk){
            const _Float16* pb = &wsl[(ot*16 + mrow)*XR + kk*32 + kg*4];
            half8 bfrag;
            *(unsigned long long*)&bfrag       = *(const unsigned long long*)pb;
            *((unsigned long long*)&bfrag + 1) = *(const unsigned long long*)(pb + 16);
            acc[ot] = __builtin_amdgcn_mfma_f32_16x16x32_f16(afrag[kk], bfrag, acc[ot], 0, 0, 0);
        }
    }
    #pragma unroll
    for (int ot = 0; ot < 4; ++ot){
        int o = ot*16 + mrow;
        float as_o = att_s[o], ad_o = att_d[o];
        #pragma unroll
        for (int r = 0; r < 4; ++r){
            float dv = acc[ot][r];
            int node = base + nodeb + kg*4 + r;
            if (node < NN) h1h[node*64 + o] = __float2half(dv);
            float ps = dv * as_o, pd = dv * ad_o;
            ps += __shfl_xor(ps, 1); ps += __shfl_xor(ps, 2); ps += __shfl_xor(ps, 4);
            pd += __shfl_xor(pd, 1); pd += __shfl_xor(pd, 2); pd += __shfl_xor(pd, 4);
            if ((lane & 7) == 0 && node < NN){
                int h = ot*2 + ((lane >> 3) & 1);
                a_src[node*8 + h] = ps;
                a_dst[node*8 + h] = pd;
            }
        }
    }
}

__global__ __launch_bounds__(256) void bucket_finalize(const unsigned* __restrict__ packed,
        const int* __restrict__ gboff, int* __restrict__ rowstart, int* __restrict__ esrc){
    __shared__ int ldeg[1 << BSH];
    __shared__ int lcur[1 << BSH];
    __shared__ int wtot[2];
    int b = blockIdx.x, t = threadIdx.x;
    if (t < (1 << BSH)) ldeg[t] = 0;
    __syncthreads();
    int p0 = gboff[b], p1 = gboff[b+1];
    for (int i = p0 + t; i < p1; i += 256)
        atomicAdd(&ldeg[packed[i] & ((1 << BSH) - 1)], 1);
    __syncthreads();
    if (t < (1 << BSH)){
        int v = ldeg[t];
        int lane = t & 63, w = t >> 6;
        int iv = v;
        #pragma unroll
        for (int off = 1; off < 64; off <<= 1){
            int u = __shfl_up(iv, off);
            if (lane >= off) iv += u;
        }
        lcur[t] = iv;
        if (lane == 63) wtot[w] = iv;
    }
    __syncthreads();
    if (t < (1 << BSH)){
        int v = ldeg[t];
        int w = t >> 6;
        int incl = lcur[t] + (w ? wtot[0] : 0);
        int rs = p0 + incl - v;       // exclusive
        int n = (b << BSH) + t;
        if (n < NN) rowstart[n] = rs;
        lcur[t] = rs;
    }
    if (b == 0 && t == 0) rowstart[NN] = ETOT;
    __syncthreads();
    for (int i = p0 + t; i < p1; i += 256){
        unsigned p = packed[i];
        int pos = atomicAdd(&lcur[p & ((1 << BSH) - 1)], 1);
        esrc[pos] = (int)(p >> 16);
    }
}

// ---------------- layer1 aggregation + fused gemm2/att2 epilogue ----------------
// one wave per node; depth-2 pipeline (R19-proven); epilogue computes
// h2[n] = elu(out1[n]) @ W2^T  via wave-local LDS row + per-lane W2 registers.
__global__ __launch_bounds__(256) void layer1_node(const int* __restrict__ rowstart,
        const int* __restrict__ esrc, const float* __restrict__ a_src,
        const float* __restrict__ a_dst, const __half* __restrict__ h1h,
        const float* __restrict__ b1, const float* __restrict__ W2,
        const float* __restrict__ att_s2, const float* __restrict__ att_d2,
        __half* __restrict__ h2h, float* __restrict__ a_src2, float* __restrict__ a_dst2){
    __shared__ float evs[4][64];     // wave-local elu(out1) rows
    int wv = threadIdx.x >> 6;
    int wid = __builtin_amdgcn_readfirstlane((blockIdx.x*256 + threadIdx.x) >> 6);
    int lane = threadIdx.x & 63;
    if (wid >= NN) return;
    int n = wid;
    int h = lane >> 3;
    // gemm2 per-lane constants (o2 = lane&15, ks2 = lane>>4); W2[o][k] row-major
    int o2 = lane & 15, ks2 = lane >> 4;
    float4 wr2[4];
    {
        const float4* W4 = reinterpret_cast<const float4*>(W2);
        #pragma unroll
        for (int j4 = 0; j4 < 4; ++j4)
            wr2[j4] = W4[o2*16 + ks2*4 + j4];
    }
    float as2_o = att_s2[o2], ad2_o = att_d2[o2];
    int r0 = rowstart[n], r1 = rowstart[n+1];
    float ad = a_dst[n*8 + h];
    float den0 = 0.f, acc0 = 0.f, den1 = 0.f, acc1 = 0.f;
    float den2 = 0.f, acc2 = 0.f, den3 = 0.f, acc3 = 0.f;
    float den4 = 0.f, acc4 = 0.f, den5 = 0.f, acc5 = 0.f;
    float den6 = 0.f, acc6 = 0.f, den7 = 0.f, acc7 = 0.f;
    int i = r0;
    int nfull = (r1 - r0) >> 3;
    if (nfull > 0){
        int s0 = esrc[i],   s1 = esrc[i+1], s2 = esrc[i+2], s3 = esrc[i+3];
        int s4 = esrc[i+4], s5 = esrc[i+5], s6 = esrc[i+6], s7 = esrc[i+7];
        float eA0 = a_src[s0*8 + h], eA1 = a_src[s1*8 + h];
        float eA2 = a_src[s2*8 + h], eA3 = a_src[s3*8 + h];
        float eA4 = a_src[s4*8 + h], eA5 = a_src[s5*8 + h];
        float eA6 = a_src[s6*8 + h], eA7 = a_src[s7*8 + h];
        float hA0 = __half2float(h1h[s0*64 + lane]);
        float hA1 = __half2float(h1h[s1*64 + lane]);
        float hA2 = __half2float(h1h[s2*64 + lane]);
        float hA3 = __half2float(h1h[s3*64 + lane]);
        float hA4 = __half2float(h1h[s4*64 + lane]);
        float hA5 = __half2float(h1h[s5*64 + lane]);
        float hA6 = __half2float(h1h[s6*64 + lane]);
        float hA7 = __half2float(h1h[s7*64 + lane]);
        i += 8;
        for (int b = 1; b < nfull; ++b){
            int t0 = esrc[i],   t1 = esrc[i+1], t2 = esrc[i+2], t3 = esrc[i+3];
            int t4 = esrc[i+4], t5 = esrc[i+5], t6 = esrc[i+6], t7 = esrc[i+7];
            float eB0 = a_src[t0*8 + h], eB1 = a_src[t1*8 + h];
            float eB2 = a_src[t2*8 + h], eB3 = a_src[t3*8 + h];
            float eB4 = a_src[t4*8 + h], eB5 = a_src[t5*8 + h];
            float eB6 = a_src[t6*8 + h], eB7 = a_src[t7*8 + h];
            float hB0 = __half2float(h1h[t0*64 + lane]);
            float hB1 = __half2float(h1h[t1*64 + lane]);
            float hB2 = __half2float(h1h[t2*64 + lane]);
            float hB3 = __half2float(h1h[t3*64 + lane]);
            float hB4 = __half2float(h1h[t4*64 + lane]);
            float hB5 = __half2float(h1h[t5*64 + lane]);
            float hB6 = __half2float(h1h[t6*64 + lane]);
            float hB7 = __half2float(h1h[t7*64 + lane]);
            i += 8;
            float p0 = __expf(leaky(eA0 + ad)), p1 = __expf(leaky(eA1 + ad));
            float p2 = __expf(leaky(eA2 + ad)), p3 = __expf(leaky(eA3 + ad));
            float p4 = __expf(leaky(eA4 + ad)), p5 = __expf(leaky(eA5 + ad));
            float p6 = __expf(leaky(eA6 + ad)), p7 = __expf(leaky(eA7 + ad));
            den0 += p0; acc0 = fmaf(p0, hA0, acc0);
            den1 += p1; acc1 = fmaf(p1, hA1, acc1);
            den2 += p2; acc2 = fmaf(p2, hA2, acc2);
            den3 += p3; acc3 = fmaf(p3, hA3, acc3);
            den4 += p4; acc4 = fmaf(p4, hA4, acc4);
            den5 += p5; acc5 = fmaf(p5, hA5, acc5);
            den6 += p6; acc6 = fmaf(p6, hA6, acc6);
            den7 += p7; acc7 = fmaf(p7, hA7, acc7);
            eA0 = eB0; eA1 = eB1; eA2 = eB2; eA3 = eB3;
            eA4 = eB4; eA5 = eB5; eA6 = eB6; eA7 = eB7;
            hA0 = hB0; hA1 = hB1; hA2 = hB2; hA3 = hB3;
            hA4 = hB4; hA5 = hB5; hA6 = hB6; hA7 = hB7;
        }
        float p0 = __expf(leaky(eA0 + ad)), p1 = __expf(leaky(eA1 + ad));
        float p2 = __expf(leaky(eA2 + ad)), p3 = __expf(leaky(eA3 + ad));
        float p4 = __expf(leaky(eA4 + ad)), p5 = __expf(leaky(eA5 + ad));
        float p6 = __expf(leaky(eA6 + ad)), p7 = __expf(leaky(eA7 + ad));
        den0 += p0; acc0 = fmaf(p0, hA0, acc0);
        den1 += p1; acc1 = fmaf(p1, hA1, acc1);
        den2 += p2; acc2 = fmaf(p2, hA2, acc2);
        den3 += p3; acc3 = fmaf(p3, hA3, acc3);
        den4 += p4; acc4 = fmaf(p4, hA4, acc4);
        den5 += p5; acc5 = fmaf(p5, hA5, acc5);
        den6 += p6; acc6 = fmaf(p6, hA6, acc6);
        den7 += p7; acc7 = fmaf(p7, hA7, acc7);
    }
    for (; i + 3 < r1; i += 4){
        int s0 = esrc[i], s1 = esrc[i+1], s2 = esrc[i+2], s3 = esrc[i+3];
        float e0 = leaky(a_src[s0*8 + h] + ad);
        float e1 = leaky(a_src[s1*8 + h] + ad);
        float e2 = leaky(a_src[s2*8 + h] + ad);
        float e3 = leaky(a_src[s3*8 + h] + ad);
        float hv0 = __half2float(h1h[s0*64 + lane]);
        float hv1 = __half2float(h1h[s1*64 + lane]);
        float hv2 = __half2float(h1h[s2*64 + lane]);
        float hv3 = __half2float(h1h[s3*64 + lane]);
        float p0 = __expf(e0), p1 = __expf(e1), p2 = __expf(e2), p3 = __expf(e3);
        den0 += p0; acc0 = fmaf(p0, hv0, acc0);
        den1 += p1; acc1 = fmaf(p1, hv1, acc1);
        den2 += p2; acc2 = fmaf(p2, hv2, acc2);
        den3 += p3; acc3 = fmaf(p3, hv3, acc3);
    }
    for (; i < r1; ++i){
        int s = esrc[i];
        float p = __expf(leaky(a_src[s*8 + h] + ad));
        den0 += p; acc0 = fmaf(p, __half2float(h1h[s*64 + lane]), acc0);
    }
    float den = ((den0 + den1) + (den2 + den3)) + ((den4 + den5) + (den6 + den7));
    float acc = ((acc0 + acc1) + (acc2 + acc3)) + ((acc4 + acc5) + (acc6 + acc7));
    // ---- fused gemm2 epilogue (out1 never materialized) ----
    float ov = acc/(den + 1e-16f) + b1[lane];
    float ev = ov > 0.f ? ov : __expf(ov) - 1.f;
    evs[wv][lane] = ev;                      // wave-local: DS ops in-order, no barrier
    float t = 0.f;
    #pragma unroll
    for (int j4 = 0; j4 < 4; ++j4){
        float4 e4 = *(const float4*)&evs[wv][ks2*16 + j4*4];
        t = fmaf(e4.x, wr2[j4].x, t);
        t = fmaf(e4.y, wr2[j4].y, t);
        t = fmaf(e4.z, wr2[j4].z, t);
        t = fmaf(e4.w, wr2[j4].w, t);
    }
    t += __shfl_xor(t, 16); t += __shfl_xor(t, 32);   // ks2-reduce: full dot for o2
    float ps = t * as2_o, pd = t * ad2_o;
    ps += __shfl_xor(ps, 1); ps += __shfl_xor(ps, 2);
    ps += __shfl_xor(ps, 4); ps += __shfl_xor(ps, 8);
    pd += __shfl_xor(pd, 1); pd += __shfl_xor(pd, 2);
    pd += __shfl_xor(pd, 4); pd += __shfl_xor(pd, 8);
    if (lane < 16) h2h[n*16 + lane] = __float2half(t);
    if (lane == 0){ a_src2[n] = ps; a_dst2[n] = pd; }
}

// one wave per node; lane = slot*16 + c; depth-2 pipeline (R20 structure)
__global__ __launch_bounds__(256) void layer2_node(const int* __restrict__ rowstart,
        const int* __restrict__ esrc, const float* __restrict__ a_src,
        const float* __restrict__ a_dst, const __half* __restrict__ h2h,
        const float* __restrict__ b2, float* __restrict__ out){
    int wid = __builtin_amdgcn_readfirstlane((blockIdx.x*256 + threadIdx.x) >> 6);
    int lane = threadIdx.x & 63;
    if (wid >= NN) return;
    int n = wid;
    int slot = lane >> 4, c = lane & 15;
    int r0 = rowstart[n], r1 = rowstart[n+1];
    float ad = a_dst[n];
    float den0 = 0.f, acc0 = 0.f, den1 = 0.f, acc1 = 0.f;
    float den2 = 0.f, acc2 = 0.f, den3 = 0.f, acc3 = 0.f;
    int i = r0 + slot;
    if (i + 12 < r1){
        int s0 = esrc[i], s1 = esrc[i+4], s2 = esrc[i+8], s3 = esrc[i+12];
        float eA0 = a_src[s0], eA1 = a_src[s1], eA2 = a_src[s2], eA3 = a_src[s3];
        float hA0 = __half2float(h2h[s0*16 + c]);
        float hA1 = __half2float(h2h[s1*16 + c]);
        float hA2 = __half2float(h2h[s2*16 + c]);
        float hA3 = __half2float(h2h[s3*16 + c]);
        i += 16;
        while (i + 12 < r1){
            int t0 = esrc[i], t1 = esrc[i+4], t2 = esrc[i+8], t3 = esrc[i+12];
            float eB0 = a_src[t0], eB1 = a_src[t1], eB2 = a_src[t2], eB3 = a_src[t3];
            float hB0 = __half2float(h2h[t0*16 + c]);
            float hB1 = __half2float(h2h[t1*16 + c]);
            float hB2 = __half2float(h2h[t2*16 + c]);
            float hB3 = __half2float(h2h[t3*16 + c]);
            i += 16;
            float p0 = __expf(leaky(eA0 + ad)), p1 = __expf(leaky(eA1 + ad));
            float p2 = __expf(leaky(eA2 + ad)), p3 = __expf(leaky(eA3 + ad));
            den0 += p0; acc0 = fmaf(p0, hA0, acc0);
            den1 += p1; acc1 = fmaf(p1, hA1, acc1);
            den2 += p2; acc2 = fmaf(p2, hA2, acc2);
            den3 += p3; acc3 = fmaf(p3, hA3, acc3);
            eA0 = eB0; eA1 = eB1; eA2 = eB2; eA3 = eB3;
            hA0 = hB0; hA1 = hB1; hA2 = hB2; hA3 = hB3;
        }
        float p0 = __expf(leaky(eA0 + ad)), p1 = __expf(leaky(eA1 + ad));
        float p2 = __expf(leaky(eA2 + ad)), p3 = __expf(leaky(eA3 + ad));
        den0 += p0; acc0 = fmaf(p0, hA0, acc0);
        den1 += p1; acc1 = fmaf(p1, hA1, acc1);
        den2 += p2; acc2 = fmaf(p2, hA2, acc2);
        den3 += p3; acc3 = fmaf(p3, hA3, acc3);
    }
    for (; i < r1; i += 4){
        int s = esrc[i];
        float p = __expf(leaky(a_src[s] + ad));
        den0 += p; acc0 = fmaf(p, __half2float(h2h[s*16 + c]), acc0);
    }
    float den = (den0 + den1) + (den2 + den3);
    float acc = (acc0 + acc1) + (acc2 + acc3);
    den += __shfl_xor(den, 16); den += __shfl_xor(den, 32);
    acc += __shfl_xor(acc, 16); acc += __shfl_xor(acc, 32);
    if (slot == 0) out[n*16 + c] = acc/(den + 1e-16f) + b2[c];
}

extern "C" void kernel_launch(void* const* d_in, const int* in_sizes, int n_in,
                              void* d_out, int out_size, void* d_ws, size_t ws_size,
                              hipStream_t stream){
    const float* x    = (const float*)d_in[0];
    const int*   ei   = (const int*)d_in[1];
    const float* W1   = (const float*)d_in[2];
    const float* as1w = (const float*)d_in[3];
    const float* ad1w = (const float*)d_in[4];
    const float* b1   = (const float*)d_in[5];
    const float* W2   = (const float*)d_in[6];
    const float* as2w = (const float*)d_in[7];
    const float* ad2w = (const float*)d_in[8];
    const float* b2   = (const float*)d_in[9];
    float* out = (float*)d_out;

    float* ws = (float*)d_ws;
    // words: h1h 32N | h2h 8N + a_src2 N + a_dst2 N (in old out1 region, DISJOINT from h1h)
    //        | rowstart N+1 | gbcnt NBUK | gboff NBUK+1 | gbcur NBUK | packed ETOT | esrc ETOT
    __half* h1h     = (__half*)ws;                      // 64N halves = 32N words
    __half* h2h     = (__half*)(ws + (size_t)32*NN);    // 16N halves = 8N words
    float* a_src2   = ws + (size_t)40*NN;               // N
    float* a_dst2   = ws + (size_t)41*NN;               // N
    int*   rowstart = (int*)(ws + (size_t)96*NN);       // N+1
    int*   gbcnt    = rowstart + NN + 1;                // NBUK
    int*   gboff    = gbcnt + NBUK;                     // NBUK+1
    int*   gbcur    = gboff + NBUK + 1;                 // NBUK
    unsigned* packed= (unsigned*)(gbcur + NBUK);        // ETOT
    int*   esrc     = (int*)(packed + ETOT);            // ETOT
    // a_src1/a_dst1 live in d_out (16N floats) until layer1_node; layer2_node overwrites d_out last
    float* a_src1 = out;                                // 8N
    float* a_dst1 = out + (size_t)8*NN;                 // 8N

    // CSR build (scatter fused with gemm1)
    hipLaunchKernelGGL(zero_gbcnt,      dim3(2), dim3(256), 0, stream, gbcnt);
    hipLaunchKernelGGL(bucket_hist,     dim3(NBLK_A), dim3(256), 0, stream, ei, gbcnt);
    hipLaunchKernelGGL(bucket_scan,     dim3(1), dim3(512), 0, stream, gbcnt, gboff, gbcur);
    hipLaunchKernelGGL(scatter_gemm1,   dim3(NBLK_A + NBLK_G1), dim3(256), 0, stream,
                       ei, gbcur, packed, x, W1, as1w, ad1w, h1h, a_src1, a_dst1);
    hipLaunchKernelGGL(bucket_finalize, dim3(NBUK), dim3(256), 0, stream, packed, gboff, rowstart, esrc);

    // layer 1 aggregation + fused gemm2/att2
    hipLaunchKernelGGL(layer1_node, dim3((NN*64 + 255)/256), dim3(256), 0, stream,
                       rowstart, esrc, a_src1, a_dst1, h1h, b1, W2, as2w, ad2w, h2h, a_src2, a_dst2);
    // layer 2
    hipLaunchKernelGGL(layer2_node, dim3((NN*64 + 255)/256), dim3(256), 0, stream,
                       rowstart, esrc, a_src2, a_dst2, h2h, b2, out);
}

// Round 22
// 115.177 us; speedup vs baseline: 1.0568x; 1.0568x over previous
//
#include <hip/hip_runtime.h>
#include <hip/hip_fp16.h>
#include <math.h>

#define NN 50000
#define NE 800000
#define ETOT (NE + NN)
#define INC 128
#define F1 64
#define NH 8
#define OC 16
#define NEG 0.2f
#define BSH 7         // 128 dsts per bucket
#define NBUK 391      // ceil(NN/128)
#define CHUNK_A 4096
#define NBLK_A ((ETOT + CHUNK_A - 1) / CHUNK_A)   // 208
#define G1TILE 64
#define NBLK_G1 ((NN + G1TILE - 1) / G1TILE)      // 782
#define XR 136        // LDS row stride in halves (+8 pad: bank-spread)

typedef _Float16 half8 __attribute__((ext_vector_type(8)));
typedef float f32x4 __attribute__((ext_vector_type(4)));

__device__ __forceinline__ float leaky(float x){ return x > 0.f ? x : NEG * x; }

__device__ __forceinline__ void getsd(const int* __restrict__ ei, int e, int& s, int& d){
    if (e < NE){ s = ei[e]; d = ei[NE + e]; }
    else { s = e - NE; d = s; }   // self-loops appended
}

// ---------------- CSR build: two-level binning (R13-proven) ----------------

__global__ __launch_bounds__(256) void zero_gbcnt(int* __restrict__ gbcnt){
    int i = blockIdx.x*256 + threadIdx.x;
    if (i < NBUK) gbcnt[i] = 0;
}

__global__ __launch_bounds__(256) void bucket_hist(const int* __restrict__ ei, int* __restrict__ gbcnt){
    __shared__ int bcnt[NBUK];
    int tid = threadIdx.x;
    for (int j = tid; j < NBUK; j += 256) bcnt[j] = 0;
    __syncthreads();
    int e0 = blockIdx.x * CHUNK_A;
    int e1 = e0 + CHUNK_A; if (e1 > ETOT) e1 = ETOT;
    for (int e = e0 + tid; e < e1; e += 256){
        int d = (e < NE) ? ei[NE + e] : e - NE;
        atomicAdd(&bcnt[d >> BSH], 1);
    }
    __syncthreads();
    for (int j = tid; j < NBUK; j += 256)
        if (bcnt[j]) atomicAdd(&gbcnt[j], bcnt[j]);
}

__global__ __launch_bounds__(512) void bucket_scan(const int* __restrict__ gbcnt,
        int* __restrict__ gboff, int* __restrict__ gbcur){
    __shared__ int s[512];
    int t = threadIdx.x;
    int v = (t < NBUK) ? gbcnt[t] : 0;
    s[t] = v; __syncthreads();
    for (int off = 1; off < 512; off <<= 1){
        int u = (t >= off) ? s[t - off] : 0;
        __syncthreads();
        s[t] += u;
        __syncthreads();
    }
    if (t < NBUK){ int ex = s[t] - v; gboff[t] = ex; gbcur[t] = ex; }
    if (t == 0) gboff[NBUK] = ETOT;
}

// fused: blocks [0, NBLK_A) = bucket_scatter; blocks [NBLK_A, NBLK_A+NBLK_G1) = MFMA gemm1 (+att1)
__global__ __launch_bounds__(256) void scatter_gemm1(const int* __restrict__ ei,
        int* __restrict__ gbcur, unsigned* __restrict__ packed,
        const float* __restrict__ x, const float* __restrict__ W1,
        const float* __restrict__ att_s, const float* __restrict__ att_d,
        __half* __restrict__ h1h, float* __restrict__ a_src, float* __restrict__ a_dst){
    __shared__ _Float16 xs[64*XR];   // 17.4 KB (scatter branch aliases as bcnt)
    __shared__ _Float16 wsl[64*XR];  // 17.4 KB
    int tid = threadIdx.x;
    if (blockIdx.x < NBLK_A){
        // ---- bucket_scatter (R13-proven; bcnt aliases xs) ----
        int* bcnt = (int*)xs;
        for (int j = tid; j < NBUK; j += 256) bcnt[j] = 0;
        __syncthreads();
        int e0 = blockIdx.x * CHUNK_A;
        int e1 = e0 + CHUNK_A; if (e1 > ETOT) e1 = ETOT;
        for (int e = e0 + tid; e < e1; e += 256){
            int d = (e < NE) ? ei[NE + e] : e - NE;
            atomicAdd(&bcnt[d >> BSH], 1);
        }
        __syncthreads();
        for (int j = tid; j < NBUK; j += 256){
            int c = bcnt[j];
            bcnt[j] = c ? atomicAdd(&gbcur[j], c) : 0;
        }
        __syncthreads();
        for (int e = e0 + tid; e < e1; e += 256){
            int s, d; getsd(ei, e, s, d);
            int pos = atomicAdd(&bcnt[d >> BSH], 1);
            packed[pos] = ((unsigned)s << 16) | (unsigned)d;
        }
        return;
    }
    // ---- MFMA gemm1 + fused att1 (R18-proven) ----
    int base = (blockIdx.x - NBLK_A) * G1TILE;
    for (int i = tid; i < F1*INC; i += 256){
        int o = i >> 7, k = i & 127;
        wsl[o*XR + k] = (_Float16)W1[i];
    }
    for (int f = tid; f < 64*32; f += 256){
        int row = f >> 5, c4 = f & 31;
        int n = base + row;
        float4 v = (n < NN) ? reinterpret_cast<const float4*>(x)[n*32 + c4]
                            : make_float4(0.f,0.f,0.f,0.f);
        _Float16* p = &xs[row*XR + c4*4];
        p[0] = (_Float16)v.x; p[1] = (_Float16)v.y;
        p[2] = (_Float16)v.z; p[3] = (_Float16)v.w;
    }
    __syncthreads();
    int w = tid >> 6, lane = tid & 63;
    int mrow = lane & 15, kg = lane >> 4;
    int nodeb = w*16;
    half8 afrag[4];
    #pragma unroll
    for (int kk = 0; kk < 4; ++kk){
        const _Float16* pa = &xs[(nodeb + mrow)*XR + kk*32 + kg*4];
        *(unsigned long long*)&afrag[kk]       = *(const unsigned long long*)pa;
        *((unsigned long long*)&afrag[kk] + 1) = *(const unsigned long long*)(pa + 16);
    }
    f32x4 acc[4];
    #pragma unroll
    for (int ot = 0; ot < 4; ++ot) acc[ot] = (f32x4){0.f,0.f,0.f,0.f};
    #pragma unroll
    for (int ot = 0; ot < 4; ++ot){
        #pragma unroll
        for (int kk = 0; kk < 4; ++kk){
            const _Float16* pb = &wsl[(ot*16 + mrow)*XR + kk*32 + kg*4];
            half8 bfrag;
            *(unsigned long long*)&bfrag       = *(const unsigned long long*)pb;
            *((unsigned long long*)&bfrag + 1) = *(const unsigned long long*)(pb + 16);
            acc[ot] = __builtin_amdgcn_mfma_f32_16x16x32_f16(afrag[kk], bfrag, acc[ot], 0, 0, 0);
        }
    }
    #pragma unroll
    for (int ot = 0; ot < 4; ++ot){
        int o = ot*16 + mrow;
        float as_o = att_s[o], ad_o = att_d[o];
        #pragma unroll
        for (int r = 0; r < 4; ++r){
            float dv = acc[ot][r];
            int node = base + nodeb + kg*4 + r;
            if (node < NN) h1h[node*64 + o] = __float2half(dv);
            float ps = dv * as_o, pd = dv * ad_o;
            ps += __shfl_xor(ps, 1); ps += __shfl_xor(ps, 2); ps += __shfl_xor(ps, 4);
            pd += __shfl_xor(pd, 1); pd += __shfl_xor(pd, 2); pd += __shfl_xor(pd, 4);
            if ((lane & 7) == 0 && node < NN){
                int h = ot*2 + ((lane >> 3) & 1);
                a_src[node*8 + h] = ps;
                a_dst[node*8 + h] = pd;
            }
        }
    }
}

__global__ __launch_bounds__(256) void bucket_finalize(const unsigned* __restrict__ packed,
        const int* __restrict__ gboff, int* __restrict__ rowstart, int* __restrict__ esrc){
    __shared__ int ldeg[1 << BSH];
    __shared__ int lcur[1 << BSH];
    __shared__ int wtot[2];
    int b = blockIdx.x, t = threadIdx.x;
    if (t < (1 << BSH)) ldeg[t] = 0;
    __syncthreads();
    int p0 = gboff[b], p1 = gboff[b+1];
    for (int i = p0 + t; i < p1; i += 256)
        atomicAdd(&ldeg[packed[i] & ((1 << BSH) - 1)], 1);
    __syncthreads();
    if (t < (1 << BSH)){
        int v = ldeg[t];
        int lane = t & 63, w = t >> 6;
        int iv = v;
        #pragma unroll
        for (int off = 1; off < 64; off <<= 1){
            int u = __shfl_up(iv, off);
            if (lane >= off) iv += u;
        }
        lcur[t] = iv;
        if (lane == 63) wtot[w] = iv;
    }
    __syncthreads();
    if (t < (1 << BSH)){
        int v = ldeg[t];
        int w = t >> 6;
        int incl = lcur[t] + (w ? wtot[0] : 0);
        int rs = p0 + incl - v;       // exclusive
        int n = (b << BSH) + t;
        if (n < NN) rowstart[n] = rs;
        lcur[t] = rs;
    }
    if (b == 0 && t == 0) rowstart[NN] = ETOT;
    __syncthreads();
    for (int i = p0 + t; i < p1; i += 256){
        unsigned p = packed[i];
        int pos = atomicAdd(&lcur[p & ((1 << BSH) - 1)], 1);
        esrc[pos] = (int)(p >> 16);
    }
}

// ---------------- gemm2 + fused att2 (R14-proven, 64-node tile) ----------------

__global__ __launch_bounds__(256, 4) void gemm2(const float* __restrict__ out1, const float* __restrict__ W2,
        const float* __restrict__ att_s, const float* __restrict__ att_d,
        __half* __restrict__ h2h, float* __restrict__ a_src, float* __restrict__ a_dst){
    __shared__ float xs2[64*80];    // [row][slice ks][20]
    int tid = threadIdx.x;
    int base = blockIdx.x * 64;
    int w = tid >> 6, lane = tid & 63;
    int o = lane >> 2, ks = lane & 3;
    float4 wr[4];
    {
        const float4* W4 = reinterpret_cast<const float4*>(W2);
        #pragma unroll
        for (int j4 = 0; j4 < 4; ++j4)
            wr[j4] = W4[o*16 + ks*4 + j4];
    }
    float as_o = att_s[o], ad_o = att_d[o];
    {
        #pragma unroll
        for (int j = 0; j < 4; ++j){
            int f = tid + 256*j;
            int row = f >> 4, c4 = f & 15;
            int n = base + row;
            float4 v = make_float4(0.f,0.f,0.f,0.f);
            if (n < NN) v = reinterpret_cast<const float4*>(out1)[n*16 + c4];
            v.x = v.x > 0.f ? v.x : __expf(v.x) - 1.f;
            v.y = v.y > 0.f ? v.y : __expf(v.y) - 1.f;
            v.z = v.z > 0.f ? v.z : __expf(v.z) - 1.f;
            v.w = v.w > 0.f ? v.w : __expf(v.w) - 1.f;
            int sk = c4 >> 2, j4 = c4 & 3;
            *(float4*)(&xs2[row*80 + sk*20 + j4*4]) = v;
        }
    }
    __syncthreads();
    for (int r = 0; r < 16; ++r){
        int row = w*16 + r;
        const float* xb = &xs2[row*80 + ks*20];
        float acc = 0.f;
        #pragma unroll
        for (int j4 = 0; j4 < 4; ++j4){
            float4 xv = *(const float4*)(xb + j4*4);
            acc = fmaf(xv.x, wr[j4].x, acc);
            acc = fmaf(xv.y, wr[j4].y, acc);
            acc = fmaf(xv.z, wr[j4].z, acc);
            acc = fmaf(xv.w, wr[j4].w, acc);
        }
        acc += __shfl_xor(acc, 1); acc += __shfl_xor(acc, 2);  // ks-reduce
        int node = base + row;
        float ps = acc * as_o, pd = acc * ad_o;
        ps += __shfl_xor(ps, 4); ps += __shfl_xor(ps, 8);
        ps += __shfl_xor(ps, 16); ps += __shfl_xor(ps, 32);
        pd += __shfl_xor(pd, 4); pd += __shfl_xor(pd, 8);
        pd += __shfl_xor(pd, 16); pd += __shfl_xor(pd, 32);
        if (node < NN){
            if (ks == 0) h2h[node*16 + o] = __float2half(acc);
            if (lane == 0){ a_src[node] = ps; a_dst[node] = pd; }
        }
    }
}

// ---------------- node-centric aggregation ----------------

// one wave per node; lane = (eh = lane>>5, c2 = lane&31): 2 channels/lane, 2 edges per load instr.
// Per 8 edges: 4 esrc + 4 a_src + 4 half2 loads (VMEM instr halved vs per-channel scheme).
__global__ __launch_bounds__(256) void layer1_node(const int* __restrict__ rowstart,
        const int* __restrict__ esrc, const float* __restrict__ a_src,
        const float* __restrict__ a_dst, const __half* __restrict__ h1h,
        const float* __restrict__ b1, float* __restrict__ out1){
    int wid = __builtin_amdgcn_readfirstlane((blockIdx.x*256 + threadIdx.x) >> 6);
    int lane = threadIdx.x & 63;
    if (wid >= NN) return;
    int n = wid;
    int c2 = lane & 31;          // channel-pair index: channels 2c2, 2c2+1
    int eh = lane >> 5;          // which edge of each pair this half-wave handles
    int h = c2 >> 2;             // head of both channels
    int r0 = rowstart[n], r1 = rowstart[n+1];
    float ad = a_dst[n*8 + h];
    const __half2* h1h2 = (const __half2*)h1h;
    float den0 = 0.f, x00 = 0.f, x01 = 0.f;
    float den1 = 0.f, x10 = 0.f, x11 = 0.f;
    float den2 = 0.f, x20 = 0.f, x21 = 0.f;
    float den3 = 0.f, x30 = 0.f, x31 = 0.f;
    int i = r0;
    for (; i + 7 < r1; i += 8){       // 8 edges = 4 pairs
        int s0 = esrc[i     + eh];
        int s1 = esrc[i + 2 + eh];
        int s2 = esrc[i + 4 + eh];
        int s3 = esrc[i + 6 + eh];
        float e0 = a_src[s0*8 + h];
        float e1 = a_src[s1*8 + h];
        float e2 = a_src[s2*8 + h];
        float e3 = a_src[s3*8 + h];
        float2 h0 = __half22float2(h1h2[s0*32 + c2]);
        float2 h1 = __half22float2(h1h2[s1*32 + c2]);
        float2 h2 = __half22float2(h1h2[s2*32 + c2]);
        float2 h3 = __half22float2(h1h2[s3*32 + c2]);
        float p0 = __expf(leaky(e0 + ad));
        float p1 = __expf(leaky(e1 + ad));
        float p2 = __expf(leaky(e2 + ad));
        float p3 = __expf(leaky(e3 + ad));
        den0 += p0; x00 = fmaf(p0, h0.x, x00); x01 = fmaf(p0, h0.y, x01);
        den1 += p1; x10 = fmaf(p1, h1.x, x10); x11 = fmaf(p1, h1.y, x11);
        den2 += p2; x20 = fmaf(p2, h2.x, x20); x21 = fmaf(p2, h2.y, x21);
        den3 += p3; x30 = fmaf(p3, h3.x, x30); x31 = fmaf(p3, h3.y, x31);
    }
    for (; i + 1 < r1; i += 2){       // leftover pairs
        int s = esrc[i + eh];
        float e = a_src[s*8 + h];
        float2 hv = __half22float2(h1h2[s*32 + c2]);
        float p = __expf(leaky(e + ad));
        den0 += p; x00 = fmaf(p, hv.x, x00); x01 = fmaf(p, hv.y, x01);
    }
    if (i < r1){                      // final odd edge: half 0 only
        int s = esrc[i];
        float e = a_src[s*8 + h];
        float2 hv = __half22float2(h1h2[s*32 + c2]);
        float p = __expf(leaky(e + ad));
        p = (eh == 0) ? p : 0.f;
        den0 += p; x00 = fmaf(p, hv.x, x00); x01 = fmaf(p, hv.y, x01);
    }
    float den = (den0 + den1) + (den2 + den3);
    float a0 = (x00 + x10) + (x20 + x30);
    float a1 = (x01 + x11) + (x21 + x31);
    den += __shfl_xor(den, 32);       // merge the two edge-halves
    a0  += __shfl_xor(a0, 32);
    a1  += __shfl_xor(a1, 32);
    if (eh == 0){
        float2 bb = reinterpret_cast<const float2*>(b1)[c2];
        float inv = 1.f/(den + 1e-16f);
        float2 o;
        o.x = a0*inv + bb.x;
        o.y = a1*inv + bb.y;
        reinterpret_cast<float2*>(out1)[n*32 + c2] = o;
    }
}

// one wave per node; lane = slot*16 + c; depth-2 pipeline (R20-proven)
__global__ __launch_bounds__(256) void layer2_node(const int* __restrict__ rowstart,
        const int* __restrict__ esrc, const float* __restrict__ a_src,
        const float* __restrict__ a_dst, const __half* __restrict__ h2h,
        const float* __restrict__ b2, float* __restrict__ out){
    int wid = __builtin_amdgcn_readfirstlane((blockIdx.x*256 + threadIdx.x) >> 6);
    int lane = threadIdx.x & 63;
    if (wid >= NN) return;
    int n = wid;
    int slot = lane >> 4, c = lane & 15;
    int r0 = rowstart[n], r1 = rowstart[n+1];
    float ad = a_dst[n];
    float den0 = 0.f, acc0 = 0.f, den1 = 0.f, acc1 = 0.f;
    float den2 = 0.f, acc2 = 0.f, den3 = 0.f, acc3 = 0.f;
    int i = r0 + slot;
    if (i + 12 < r1){
        int s0 = esrc[i], s1 = esrc[i+4], s2 = esrc[i+8], s3 = esrc[i+12];
        float eA0 = a_src[s0], eA1 = a_src[s1], eA2 = a_src[s2], eA3 = a_src[s3];
        float hA0 = __half2float(h2h[s0*16 + c]);
        float hA1 = __half2float(h2h[s1*16 + c]);
        float hA2 = __half2float(h2h[s2*16 + c]);
        float hA3 = __half2float(h2h[s3*16 + c]);
        i += 16;
        while (i + 12 < r1){
            int t0 = esrc[i], t1 = esrc[i+4], t2 = esrc[i+8], t3 = esrc[i+12];
            float eB0 = a_src[t0], eB1 = a_src[t1], eB2 = a_src[t2], eB3 = a_src[t3];
            float hB0 = __half2float(h2h[t0*16 + c]);
            float hB1 = __half2float(h2h[t1*16 + c]);
            float hB2 = __half2float(h2h[t2*16 + c]);
            float hB3 = __half2float(h2h[t3*16 + c]);
            i += 16;
            float p0 = __expf(leaky(eA0 + ad)), p1 = __expf(leaky(eA1 + ad));
            float p2 = __expf(leaky(eA2 + ad)), p3 = __expf(leaky(eA3 + ad));
            den0 += p0; acc0 = fmaf(p0, hA0, acc0);
            den1 += p1; acc1 = fmaf(p1, hA1, acc1);
            den2 += p2; acc2 = fmaf(p2, hA2, acc2);
            den3 += p3; acc3 = fmaf(p3, hA3, acc3);
            eA0 = eB0; eA1 = eB1; eA2 = eB2; eA3 = eB3;
            hA0 = hB0; hA1 = hB1; hA2 = hB2; hA3 = hB3;
        }
        float p0 = __expf(leaky(eA0 + ad)), p1 = __expf(leaky(eA1 + ad));
        float p2 = __expf(leaky(eA2 + ad)), p3 = __expf(leaky(eA3 + ad));
        den0 += p0; acc0 = fmaf(p0, hA0, acc0);
        den1 += p1; acc1 = fmaf(p1, hA1, acc1);
        den2 += p2; acc2 = fmaf(p2, hA2, acc2);
        den3 += p3; acc3 = fmaf(p3, hA3, acc3);
    }
    for (; i < r1; i += 4){
        int s = esrc[i];
        float p = __expf(leaky(a_src[s] + ad));
        den0 += p; acc0 = fmaf(p, __half2float(h2h[s*16 + c]), acc0);
    }
    float den = (den0 + den1) + (den2 + den3);
    float acc = (acc0 + acc1) + (acc2 + acc3);
    den += __shfl_xor(den, 16); den += __shfl_xor(den, 32);
    acc += __shfl_xor(acc, 16); acc += __shfl_xor(acc, 32);
    if (slot == 0) out[n*16 + c] = acc/(den + 1e-16f) + b2[c];
}

extern "C" void kernel_launch(void* const* d_in, const int* in_sizes, int n_in,
                              void* d_out, int out_size, void* d_ws, size_t ws_size,
                              hipStream_t stream){
    const float* x    = (const float*)d_in[0];
    const int*   ei   = (const int*)d_in[1];
    const float* W1   = (const float*)d_in[2];
    const float* as1w = (const float*)d_in[3];
    const float* ad1w = (const float*)d_in[4];
    const float* b1   = (const float*)d_in[5];
    const float* W2   = (const float*)d_in[6];
    const float* as2w = (const float*)d_in[7];
    const float* ad2w = (const float*)d_in[8];
    const float* b2   = (const float*)d_in[9];
    float* out = (float*)d_out;

    float* ws = (float*)d_ws;
    // words: h1h 32N | out1 64N | rowstart N+1 | gbcnt NBUK | gboff NBUK+1 | gbcur NBUK |
    //        packed ETOT | esrc ETOT  (~25.9 MB)
    __half* h1h     = (__half*)ws;                      // 64N halves = 32N words
    float* out1     = ws + (size_t)32*NN;               // 64N
    int*   rowstart = (int*)(ws + (size_t)96*NN);       // N+1
    int*   gbcnt    = rowstart + NN + 1;                // NBUK
    int*   gboff    = gbcnt + NBUK;                     // NBUK+1
    int*   gbcur    = gboff + NBUK + 1;                 // NBUK
    unsigned* packed= (unsigned*)(gbcur + NBUK);        // ETOT
    int*   esrc     = (int*)(packed + ETOT);            // ETOT
    // a_src1/a_dst1 live in d_out (16N floats) until layer1_node; layer2_node overwrites d_out last
    float* a_src1 = out;                                // 8N
    float* a_dst1 = out + (size_t)8*NN;                 // 8N
    __half* h2h   = h1h;                                // 16N halves (h1h dead after layer1_node)
    float* a_src2 = ws + (size_t)8*NN;                  // N (after h2h's 8N words)
    float* a_dst2 = a_src2 + NN;                        // N

    // CSR build (scatter fused with gemm1)
    hipLaunchKernelGGL(zero_gbcnt,      dim3(2), dim3(256), 0, stream, gbcnt);
    hipLaunchKernelGGL(bucket_hist,     dim3(NBLK_A), dim3(256), 0, stream, ei, gbcnt);
    hipLaunchKernelGGL(bucket_scan,     dim3(1), dim3(512), 0, stream, gbcnt, gboff, gbcur);
    hipLaunchKernelGGL(scatter_gemm1,   dim3(NBLK_A + NBLK_G1), dim3(256), 0, stream,
                       ei, gbcur, packed, x, W1, as1w, ad1w, h1h, a_src1, a_dst1);
    hipLaunchKernelGGL(bucket_finalize, dim3(NBUK), dim3(256), 0, stream, packed, gboff, rowstart, esrc);

    hipLaunchKernelGGL(layer1_node, dim3((NN*64 + 255)/256), dim3(256), 0, stream,
                       rowstart, esrc, a_src1, a_dst1, h1h, b1, out1);
    // layer 2 (att2 fused into gemm2)
    hipLaunchKernelGGL(gemm2, dim3((NN + 63)/64), dim3(256), 0, stream, out1, W2, as2w, ad2w, h2h, a_src2, a_dst2);
    hipLaunchKernelGGL(layer2_node, dim3((NN*64 + 255)/256), dim3(256), 0, stream,
                       rowstart, esrc, a_src2, a_dst2, h2h, b2, out);
}

// Round 23
// 111.781 us; speedup vs baseline: 1.0889x; 1.0304x over previous
//
#include <hip/hip_runtime.h>
#include <hip/hip_fp16.h>
#include <math.h>

#define NN 50000
#define NE 800000
#define ETOT (NE + NN)
#define INC 128
#define F1 64
#define NH 8
#define OC 16
#define NEG 0.2f
#define BSH 7         // 128 dsts per bucket
#define NBUK 391      // ceil(NN/128)
#define CHUNK_A 4096
#define NBLK_A ((ETOT + CHUNK_A - 1) / CHUNK_A)   // 208
#define G1TILE 64
#define NBLK_G1 ((NN + G1TILE - 1) / G1TILE)      // 782
#define XR 136        // LDS row stride in halves (+8 pad: bank-spread)

typedef _Float16 half8 __attribute__((ext_vector_type(8)));
typedef float f32x4 __attribute__((ext_vector_type(4)));

__device__ __forceinline__ float leaky(float x){ return x > 0.f ? x : NEG * x; }

__device__ __forceinline__ void getsd(const int* __restrict__ ei, int e, int& s, int& d){
    if (e < NE){ s = ei[e]; d = ei[NE + e]; }
    else { s = e - NE; d = s; }   // self-loops appended
}

// ---------------- CSR build: two-level binning ----------------

// per-block LDS hist -> blkcnt row (plain stores: no zero kernel, no global atomics)
__global__ __launch_bounds__(256) void bucket_hist(const int* __restrict__ ei, int* __restrict__ blkcnt){
    __shared__ int bcnt[NBUK];
    int tid = threadIdx.x;
    for (int j = tid; j < NBUK; j += 256) bcnt[j] = 0;
    __syncthreads();
    int e0 = blockIdx.x * CHUNK_A;
    int e1 = e0 + CHUNK_A; if (e1 > ETOT) e1 = ETOT;
    for (int e = e0 + tid; e < e1; e += 256){
        int d = (e < NE) ? ei[NE + e] : e - NE;
        atomicAdd(&bcnt[d >> BSH], 1);
    }
    __syncthreads();
    for (int j = tid; j < NBUK; j += 256)
        blkcnt[blockIdx.x*NBUK + j] = bcnt[j];
}

// 1 block: column-sum blkcnt then exclusive scan
__global__ __launch_bounds__(512) void bucket_scan(const int* __restrict__ blkcnt,
        int* __restrict__ gboff, int* __restrict__ gbcur){
    __shared__ int s[512];
    int t = threadIdx.x;
    int v = 0;
    if (t < NBUK){
        for (int b = 0; b < NBLK_A; ++b)
            v += blkcnt[b*NBUK + t];
    }
    s[t] = v; __syncthreads();
    for (int off = 1; off < 512; off <<= 1){
        int u = (t >= off) ? s[t - off] : 0;
        __syncthreads();
        s[t] += u;
        __syncthreads();
    }
    if (t < NBUK){ int ex = s[t] - v; gboff[t] = ex; gbcur[t] = ex; }
    if (t == 0) gboff[NBUK] = ETOT;
}

// fused: blocks [0, NBLK_A) = bucket_scatter; blocks [NBLK_A, NBLK_A+NBLK_G1) = MFMA gemm1 (+att1)
__global__ __launch_bounds__(256) void scatter_gemm1(const int* __restrict__ ei,
        int* __restrict__ gbcur, unsigned* __restrict__ packed,
        const float* __restrict__ x, const float* __restrict__ W1,
        const float* __restrict__ att_s, const float* __restrict__ att_d,
        __half* __restrict__ h1h, float* __restrict__ a_src, float* __restrict__ a_dst){
    __shared__ _Float16 xs[64*XR];   // 17.4 KB (scatter branch aliases as bcnt)
    __shared__ _Float16 wsl[64*XR];  // 17.4 KB
    int tid = threadIdx.x;
    if (blockIdx.x < NBLK_A){
        // ---- bucket_scatter (R13-proven; bcnt aliases xs) ----
        int* bcnt = (int*)xs;
        for (int j = tid; j < NBUK; j += 256) bcnt[j] = 0;
        __syncthreads();
        int e0 = blockIdx.x * CHUNK_A;
        int e1 = e0 + CHUNK_A; if (e1 > ETOT) e1 = ETOT;
        for (int e = e0 + tid; e < e1; e += 256){
            int d = (e < NE) ? ei[NE + e] : e - NE;
            atomicAdd(&bcnt[d >> BSH], 1);
        }
        __syncthreads();
        for (int j = tid; j < NBUK; j += 256){
            int c = bcnt[j];
            bcnt[j] = c ? atomicAdd(&gbcur[j], c) : 0;
        }
        __syncthreads();
        for (int e = e0 + tid; e < e1; e += 256){
            int s, d; getsd(ei, e, s, d);
            int pos = atomicAdd(&bcnt[d >> BSH], 1);
            packed[pos] = ((unsigned)s << 16) | (unsigned)d;
        }
        return;
    }
    // ---- MFMA gemm1 + fused att1 (R18-proven) ----
    int base = (blockIdx.x - NBLK_A) * G1TILE;
    for (int i = tid; i < F1*INC; i += 256){
        int o = i >> 7, k = i & 127;
        wsl[o*XR + k] = (_Float16)W1[i];
    }
    for (int f = tid; f < 64*32; f += 256){
        int row = f >> 5, c4 = f & 31;
        int n = base + row;
        float4 v = (n < NN) ? reinterpret_cast<const float4*>(x)[n*32 + c4]
                            : make_float4(0.f,0.f,0.f,0.f);
        _Float16* p = &xs[row*XR + c4*4];
        p[0] = (_Float16)v.x; p[1] = (_Float16)v.y;
        p[2] = (_Float16)v.z; p[3] = (_Float16)v.w;
    }
    __syncthreads();
    int w = tid >> 6, lane = tid & 63;
    int mrow = lane & 15, kg = lane >> 4;
    int nodeb = w*16;
    half8 afrag[4];
    #pragma unroll
    for (int kk = 0; kk < 4; ++kk){
        const _Float16* pa = &xs[(nodeb + mrow)*XR + kk*32 + kg*4];
        *(unsigned long long*)&afrag[kk]       = *(const unsigned long long*)pa;
        *((unsigned long long*)&afrag[kk] + 1) = *(const unsigned long long*)(pa + 16);
    }
    f32x4 acc[4];
    #pragma unroll
    for (int ot = 0; ot < 4; ++ot) acc[ot] = (f32x4){0.f,0.f,0.f,0.f};
    #pragma unroll
    for (int ot = 0; ot < 4; ++ot){
        #pragma unroll
        for (int kk = 0; kk < 4; ++kk){
            const _Float16* pb = &wsl[(ot*16 + mrow)*XR + kk*32 + kg*4];
            half8 bfrag;
            *(unsigned long long*)&bfrag       = *(const unsigned long long*)pb;
            *((unsigned long long*)&bfrag + 1) = *(const unsigned long long*)(pb + 16);
            acc[ot] = __builtin_amdgcn_mfma_f32_16x16x32_f16(afrag[kk], bfrag, acc[ot], 0, 0, 0);
        }
    }
    #pragma unroll
    for (int ot = 0; ot < 4; ++ot){
        int o = ot*16 + mrow;
        float as_o = att_s[o], ad_o = att_d[o];
        #pragma unroll
        for (int r = 0; r < 4; ++r){
            float dv = acc[ot][r];
            int node = base + nodeb + kg*4 + r;
            if (node < NN) h1h[node*64 + o] = __float2half(dv);
            float ps = dv * as_o, pd = dv * ad_o;
            ps += __shfl_xor(ps, 1); ps += __shfl_xor(ps, 2); ps += __shfl_xor(ps, 4);
            pd += __shfl_xor(pd, 1); pd += __shfl_xor(pd, 2); pd += __shfl_xor(pd, 4);
            if ((lane & 7) == 0 && node < NN){
                int h = ot*2 + ((lane >> 3) & 1);
                a_src[node*8 + h] = ps;
                a_dst[node*8 + h] = pd;
            }
        }
    }
}

__global__ __launch_bounds__(256) void bucket_finalize(const unsigned* __restrict__ packed,
        const int* __restrict__ gboff, int* __restrict__ rowstart, int* __restrict__ esrc){
    __shared__ int ldeg[1 << BSH];
    __shared__ int lcur[1 << BSH];
    __shared__ int wtot[2];
    int b = blockIdx.x, t = threadIdx.x;
    if (t < (1 << BSH)) ldeg[t] = 0;
    __syncthreads();
    int p0 = gboff[b], p1 = gboff[b+1];
    for (int i = p0 + t; i < p1; i += 256)
        atomicAdd(&ldeg[packed[i] & ((1 << BSH) - 1)], 1);
    __syncthreads();
    if (t < (1 << BSH)){
        int v = ldeg[t];
        int lane = t & 63, w = t >> 6;
        int iv = v;
        #pragma unroll
        for (int off = 1; off < 64; off <<= 1){
            int u = __shfl_up(iv, off);
            if (lane >= off) iv += u;
        }
        lcur[t] = iv;
        if (lane == 63) wtot[w] = iv;
    }
    __syncthreads();
    if (t < (1 << BSH)){
        int v = ldeg[t];
        int w = t >> 6;
        int incl = lcur[t] + (w ? wtot[0] : 0);
        int rs = p0 + incl - v;       // exclusive
        int n = (b << BSH) + t;
        if (n < NN) rowstart[n] = rs;
        lcur[t] = rs;
    }
    if (b == 0 && t == 0) rowstart[NN] = ETOT;
    __syncthreads();
    for (int i = p0 + t; i < p1; i += 256){
        unsigned p = packed[i];
        int pos = atomicAdd(&lcur[p & ((1 << BSH) - 1)], 1);
        esrc[pos] = (int)(p >> 16);
    }
}

// ---------------- gemm2 + fused att2 (R14-proven, 64-node tile) ----------------

__global__ __launch_bounds__(256, 4) void gemm2(const float* __restrict__ out1, const float* __restrict__ W2,
        const float* __restrict__ att_s, const float* __restrict__ att_d,
        __half* __restrict__ h2h, float* __restrict__ a_src, float* __restrict__ a_dst){
    __shared__ float xs2[64*80];    // [row][slice ks][20]
    int tid = threadIdx.x;
    int base = blockIdx.x * 64;
    int w = tid >> 6, lane = tid & 63;
    int o = lane >> 2, ks = lane & 3;
    float4 wr[4];
    {
        const float4* W4 = reinterpret_cast<const float4*>(W2);
        #pragma unroll
        for (int j4 = 0; j4 < 4; ++j4)
            wr[j4] = W4[o*16 + ks*4 + j4];
    }
    float as_o = att_s[o], ad_o = att_d[o];
    {
        #pragma unroll
        for (int j = 0; j < 4; ++j){
            int f = tid + 256*j;
            int row = f >> 4, c4 = f & 15;
            int n = base + row;
            float4 v = make_float4(0.f,0.f,0.f,0.f);
            if (n < NN) v = reinterpret_cast<const float4*>(out1)[n*16 + c4];
            v.x = v.x > 0.f ? v.x : __expf(v.x) - 1.f;
            v.y = v.y > 0.f ? v.y : __expf(v.y) - 1.f;
            v.z = v.z > 0.f ? v.z : __expf(v.z) - 1.f;
            v.w = v.w > 0.f ? v.w : __expf(v.w) - 1.f;
            int sk = c4 >> 2, j4 = c4 & 3;
            *(float4*)(&xs2[row*80 + sk*20 + j4*4]) = v;
        }
    }
    __syncthreads();
    for (int r = 0; r < 16; ++r){
        int row = w*16 + r;
        const float* xb = &xs2[row*80 + ks*20];
        float acc = 0.f;
        #pragma unroll
        for (int j4 = 0; j4 < 4; ++j4){
            float4 xv = *(const float4*)(xb + j4*4);
            acc = fmaf(xv.x, wr[j4].x, acc);
            acc = fmaf(xv.y, wr[j4].y, acc);
            acc = fmaf(xv.z, wr[j4].z, acc);
            acc = fmaf(xv.w, wr[j4].w, acc);
        }
        acc += __shfl_xor(acc, 1); acc += __shfl_xor(acc, 2);  // ks-reduce
        int node = base + row;
        float ps = acc * as_o, pd = acc * ad_o;
        ps += __shfl_xor(ps, 4); ps += __shfl_xor(ps, 8);
        ps += __shfl_xor(ps, 16); ps += __shfl_xor(ps, 32);
        pd += __shfl_xor(pd, 4); pd += __shfl_xor(pd, 8);
        pd += __shfl_xor(pd, 16); pd += __shfl_xor(pd, 32);
        if (node < NN){
            if (ks == 0) h2h[node*16 + o] = __float2half(acc);
            if (lane == 0){ a_src[node] = ps; a_dst[node] = pd; }
        }
    }
}

// ---------------- node-centric aggregation (R19-proven) ----------------

// one wave per node; depth-2 software pipeline over 8-edge batches
__global__ __launch_bounds__(256) void layer1_node(const int* __restrict__ rowstart,
        const int* __restrict__ esrc, const float* __restrict__ a_src,
        const float* __restrict__ a_dst, const __half* __restrict__ h1h,
        const float* __restrict__ b1, float* __restrict__ out1){
    int wid = __builtin_amdgcn_readfirstlane((blockIdx.x*256 + threadIdx.x) >> 6);
    int lane = threadIdx.x & 63;
    if (wid >= NN) return;
    int n = wid;
    int h = lane >> 3;
    int r0 = rowstart[n], r1 = rowstart[n+1];
    float ad = a_dst[n*8 + h];
    float den0 = 0.f, acc0 = 0.f, den1 = 0.f, acc1 = 0.f;
    float den2 = 0.f, acc2 = 0.f, den3 = 0.f, acc3 = 0.f;
    float den4 = 0.f, acc4 = 0.f, den5 = 0.f, acc5 = 0.f;
    float den6 = 0.f, acc6 = 0.f, den7 = 0.f, acc7 = 0.f;
    int i = r0;
    int nfull = (r1 - r0) >> 3;
    if (nfull > 0){
        int s0 = esrc[i],   s1 = esrc[i+1], s2 = esrc[i+2], s3 = esrc[i+3];
        int s4 = esrc[i+4], s5 = esrc[i+5], s6 = esrc[i+6], s7 = esrc[i+7];
        float eA0 = a_src[s0*8 + h], eA1 = a_src[s1*8 + h];
        float eA2 = a_src[s2*8 + h], eA3 = a_src[s3*8 + h];
        float eA4 = a_src[s4*8 + h], eA5 = a_src[s5*8 + h];
        float eA6 = a_src[s6*8 + h], eA7 = a_src[s7*8 + h];
        float hA0 = __half2float(h1h[s0*64 + lane]);
        float hA1 = __half2float(h1h[s1*64 + lane]);
        float hA2 = __half2float(h1h[s2*64 + lane]);
        float hA3 = __half2float(h1h[s3*64 + lane]);
        float hA4 = __half2float(h1h[s4*64 + lane]);
        float hA5 = __half2float(h1h[s5*64 + lane]);
        float hA6 = __half2float(h1h[s6*64 + lane]);
        float hA7 = __half2float(h1h[s7*64 + lane]);
        i += 8;
        for (int b = 1; b < nfull; ++b){
            int t0 = esrc[i],   t1 = esrc[i+1], t2 = esrc[i+2], t3 = esrc[i+3];
            int t4 = esrc[i+4], t5 = esrc[i+5], t6 = esrc[i+6], t7 = esrc[i+7];
            float eB0 = a_src[t0*8 + h], eB1 = a_src[t1*8 + h];
            float eB2 = a_src[t2*8 + h], eB3 = a_src[t3*8 + h];
            float eB4 = a_src[t4*8 + h], eB5 = a_src[t5*8 + h];
            float eB6 = a_src[t6*8 + h], eB7 = a_src[t7*8 + h];
            float hB0 = __half2float(h1h[t0*64 + lane]);
            float hB1 = __half2float(h1h[t1*64 + lane]);
            float hB2 = __half2float(h1h[t2*64 + lane]);
            float hB3 = __half2float(h1h[t3*64 + lane]);
            float hB4 = __half2float(h1h[t4*64 + lane]);
            float hB5 = __half2float(h1h[t5*64 + lane]);
            float hB6 = __half2float(h1h[t6*64 + lane]);
            float hB7 = __half2float(h1h[t7*64 + lane]);
            i += 8;
            float p0 = __expf(leaky(eA0 + ad)), p1 = __expf(leaky(eA1 + ad));
            float p2 = __expf(leaky(eA2 + ad)), p3 = __expf(leaky(eA3 + ad));
            float p4 = __expf(leaky(eA4 + ad)), p5 = __expf(leaky(eA5 + ad));
            float p6 = __expf(leaky(eA6 + ad)), p7 = __expf(leaky(eA7 + ad));
            den0 += p0; acc0 = fmaf(p0, hA0, acc0);
            den1 += p1; acc1 = fmaf(p1, hA1, acc1);
            den2 += p2; acc2 = fmaf(p2, hA2, acc2);
            den3 += p3; acc3 = fmaf(p3, hA3, acc3);
            den4 += p4; acc4 = fmaf(p4, hA4, acc4);
            den5 += p5; acc5 = fmaf(p5, hA5, acc5);
            den6 += p6; acc6 = fmaf(p6, hA6, acc6);
            den7 += p7; acc7 = fmaf(p7, hA7, acc7);
            eA0 = eB0; eA1 = eB1; eA2 = eB2; eA3 = eB3;
            eA4 = eB4; eA5 = eB5; eA6 = eB6; eA7 = eB7;
            hA0 = hB0; hA1 = hB1; hA2 = hB2; hA3 = hB3;
            hA4 = hB4; hA5 = hB5; hA6 = hB6; hA7 = hB7;
        }
        float p0 = __expf(leaky(eA0 + ad)), p1 = __expf(leaky(eA1 + ad));
        float p2 = __expf(leaky(eA2 + ad)), p3 = __expf(leaky(eA3 + ad));
        float p4 = __expf(leaky(eA4 + ad)), p5 = __expf(leaky(eA5 + ad));
        float p6 = __expf(leaky(eA6 + ad)), p7 = __expf(leaky(eA7 + ad));
        den0 += p0; acc0 = fmaf(p0, hA0, acc0);
        den1 += p1; acc1 = fmaf(p1, hA1, acc1);
        den2 += p2; acc2 = fmaf(p2, hA2, acc2);
        den3 += p3; acc3 = fmaf(p3, hA3, acc3);
        den4 += p4; acc4 = fmaf(p4, hA4, acc4);
        den5 += p5; acc5 = fmaf(p5, hA5, acc5);
        den6 += p6; acc6 = fmaf(p6, hA6, acc6);
        den7 += p7; acc7 = fmaf(p7, hA7, acc7);
    }
    for (; i + 3 < r1; i += 4){
        int s0 = esrc[i], s1 = esrc[i+1], s2 = esrc[i+2], s3 = esrc[i+3];
        float e0 = leaky(a_src[s0*8 + h] + ad);
        float e1 = leaky(a_src[s1*8 + h] + ad);
        float e2 = leaky(a_src[s2*8 + h] + ad);
        float e3 = leaky(a_src[s3*8 + h] + ad);
        float hv0 = __half2float(h1h[s0*64 + lane]);
        float hv1 = __half2float(h1h[s1*64 + lane]);
        float hv2 = __half2float(h1h[s2*64 + lane]);
        float hv3 = __half2float(h1h[s3*64 + lane]);
        float p0 = __expf(e0), p1 = __expf(e1), p2 = __expf(e2), p3 = __expf(e3);
        den0 += p0; acc0 = fmaf(p0, hv0, acc0);
        den1 += p1; acc1 = fmaf(p1, hv1, acc1);
        den2 += p2; acc2 = fmaf(p2, hv2, acc2);
        den3 += p3; acc3 = fmaf(p3, hv3, acc3);
    }
    for (; i < r1; ++i){
        int s = esrc[i];
        float p = __expf(leaky(a_src[s*8 + h] + ad));
        den0 += p; acc0 = fmaf(p, __half2float(h1h[s*64 + lane]), acc0);
    }
    float den = ((den0 + den1) + (den2 + den3)) + ((den4 + den5) + (den6 + den7));
    float acc = ((acc0 + acc1) + (acc2 + acc3)) + ((acc4 + acc5) + (acc6 + acc7));
    out1[n*64 + lane] = acc/(den + 1e-16f) + b1[lane];
}

// one wave per node; lane = slot*16 + c; 4 slots x unroll-4 (R19-proven)
__global__ __launch_bounds__(256) void layer2_node(const int* __restrict__ rowstart,
        const int* __restrict__ esrc, const float* __restrict__ a_src,
        const float* __restrict__ a_dst, const __half* __restrict__ h2h,
        const float* __restrict__ b2, float* __restrict__ out){
    int wid = __builtin_amdgcn_readfirstlane((blockIdx.x*256 + threadIdx.x) >> 6);
    int lane = threadIdx.x & 63;
    if (wid >= NN) return;
    int n = wid;
    int slot = lane >> 4, c = lane & 15;
    int r0 = rowstart[n], r1 = rowstart[n+1];
    float ad = a_dst[n];
    float den0 = 0.f, acc0 = 0.f, den1 = 0.f, acc1 = 0.f;
    float den2 = 0.f, acc2 = 0.f, den3 = 0.f, acc3 = 0.f;
    int i = r0 + slot;
    for (; i + 12 < r1; i += 16){
        int s0 = esrc[i], s1 = esrc[i+4], s2 = esrc[i+8], s3 = esrc[i+12];
        float p0 = __expf(leaky(a_src[s0] + ad));
        float p1 = __expf(leaky(a_src[s1] + ad));
        float p2 = __expf(leaky(a_src[s2] + ad));
        float p3 = __expf(leaky(a_src[s3] + ad));
        float hv0 = __half2float(h2h[s0*16 + c]);
        float hv1 = __half2float(h2h[s1*16 + c]);
        float hv2 = __half2float(h2h[s2*16 + c]);
        float hv3 = __half2float(h2h[s3*16 + c]);
        den0 += p0; acc0 = fmaf(p0, hv0, acc0);
        den1 += p1; acc1 = fmaf(p1, hv1, acc1);
        den2 += p2; acc2 = fmaf(p2, hv2, acc2);
        den3 += p3; acc3 = fmaf(p3, hv3, acc3);
    }
    for (; i < r1; i += 4){
        int s = esrc[i];
        float p = __expf(leaky(a_src[s] + ad));
        den0 += p; acc0 = fmaf(p, __half2float(h2h[s*16 + c]), acc0);
    }
    float den = (den0 + den1) + (den2 + den3);
    float acc = (acc0 + acc1) + (acc2 + acc3);
    den += __shfl_xor(den, 16); den += __shfl_xor(den, 32);
    acc += __shfl_xor(acc, 16); acc += __shfl_xor(acc, 32);
    if (slot == 0) out[n*16 + c] = acc/(den + 1e-16f) + b2[c];
}

extern "C" void kernel_launch(void* const* d_in, const int* in_sizes, int n_in,
                              void* d_out, int out_size, void* d_ws, size_t ws_size,
                              hipStream_t stream){
    const float* x    = (const float*)d_in[0];
    const int*   ei   = (const int*)d_in[1];
    const float* W1   = (const float*)d_in[2];
    const float* as1w = (const float*)d_in[3];
    const float* ad1w = (const float*)d_in[4];
    const float* b1   = (const float*)d_in[5];
    const float* W2   = (const float*)d_in[6];
    const float* as2w = (const float*)d_in[7];
    const float* ad2w = (const float*)d_in[8];
    const float* b2   = (const float*)d_in[9];
    float* out = (float*)d_out;

    float* ws = (float*)d_ws;
    // words: h1h 32N | out1 64N | rowstart N+1 | gboff NBUK+1 | gbcur NBUK |
    //        blkcnt NBLK_A*NBUK | packed ETOT | esrc ETOT  (~26.2 MB)
    __half* h1h     = (__half*)ws;                      // 64N halves = 32N words
    float* out1     = ws + (size_t)32*NN;               // 64N
    int*   rowstart = (int*)(ws + (size_t)96*NN);       // N+1
    int*   gboff    = rowstart + NN + 1;                // NBUK+1
    int*   gbcur    = gboff + NBUK + 1;                 // NBUK
    int*   blkcnt   = gbcur + NBUK;                     // NBLK_A*NBUK
    unsigned* packed= (unsigned*)(blkcnt + NBLK_A*NBUK);// ETOT
    int*   esrc     = (int*)(packed + ETOT);            // ETOT
    // a_src1/a_dst1 live in d_out (16N floats) until layer1_node; layer2_node overwrites d_out last
    float* a_src1 = out;                                // 8N
    float* a_dst1 = out + (size_t)8*NN;                 // 8N
    __half* h2h   = h1h;                                // 16N halves (h1h dead after layer1_node)
    float* a_src2 = ws + (size_t)8*NN;                  // N (after h2h's 8N words)
    float* a_dst2 = a_src2 + NN;                        // N

    // CSR build (no zero kernel: hist writes full blkcnt rows; scan column-sums)
    hipLaunchKernelGGL(bucket_hist,     dim3(NBLK_A), dim3(256), 0, stream, ei, blkcnt);
    hipLaunchKernelGGL(bucket_scan,     dim3(1), dim3(512), 0, stream, blkcnt, gboff, gbcur);
    hipLaunchKernelGGL(scatter_gemm1,   dim3(NBLK_A + NBLK_G1), dim3(256), 0, stream,
                       ei, gbcur, packed, x, W1, as1w, ad1w, h1h, a_src1, a_dst1);
    hipLaunchKernelGGL(bucket_finalize, dim3(NBUK), dim3(256), 0, stream, packed, gboff, rowstart, esrc);

    hipLaunchKernelGGL(layer1_node, dim3((NN*64 + 255)/256), dim3(256), 0, stream,
                       rowstart, esrc, a_src1, a_dst1, h1h, b1, out1);
    // layer 2 (att2 fused into gemm2)
    hipLaunchKernelGGL(gemm2, dim3((NN + 63)/64), dim3(256), 0, stream, out1, W2, as2w, ad2w, h2h, a_src2, a_dst2);
    hipLaunchKernelGGL(layer2_node, dim3((NN*64 + 255)/256), dim3(256), 0, stream,
                       rowstart, esrc, a_src2, a_dst2, h2h, b2, out);
}